// Round 11
// baseline (72812.787 us; speedup 1.0000x reference)
//
// R11: R10 persistent kernel with the ws-aliasing bug fixed: gen was at
// cnt+64 unsigneds = byte 256 = one past alloc(256) -> aliased mem[0];
// phase E's mem[0] store corrupted the barrier generation word every step.
// Now cnt and gen get separate 256-byte slots. Phases unchanged (verbatim
// R9 ports; fp64 accumulate + fp64 state; output bit-identical to R9).
#include <hip/hip_runtime.h>
#include <math.h>

#define T_ 128
#define NBLK 256

__device__ __forceinline__ double sigm_d(double x) { return 1.0 / (1.0 + exp(-x)); }

// ---- software grid barrier (all NBLK blocks co-resident by construction) ----
__device__ __forceinline__ void gsync(unsigned* cnt, unsigned* gen) {
  __threadfence();                 // every thread: drain its stores device-wide
  __syncthreads();
  if (threadIdx.x == 0) {
    unsigned g = __hip_atomic_load(gen, __ATOMIC_RELAXED, __HIP_MEMORY_SCOPE_AGENT);
    unsigned a = __hip_atomic_fetch_add(cnt, 1u, __ATOMIC_ACQ_REL, __HIP_MEMORY_SCOPE_AGENT);
    if (a == NBLK - 1u) {
      __hip_atomic_store(cnt, 0u, __ATOMIC_RELAXED, __HIP_MEMORY_SCOPE_AGENT);
      __hip_atomic_store(gen, g + 1u, __ATOMIC_RELEASE, __HIP_MEMORY_SCOPE_AGENT);
    } else {
      while (__hip_atomic_load(gen, __ATOMIC_ACQUIRE, __HIP_MEMORY_SCOPE_AGENT) == g)
        __builtin_amdgcn_s_sleep(1);
    }
  }
  __syncthreads();
}

// ---------------------------------------------------------------------------
// 32x32-tile GEMM job with register-prefetch staging:
// C_tile[32x32] = A[32 rows][0:1024] x W[0:1024][n_off:+32]
// A: AT* (double/float, row stride lda) -> fp64 LDS As[32][65].
// W: fp32 [1024][ldw] -> fp32 LDS Ws[64][36], cvt at use.
// ---------------------------------------------------------------------------
template<typename AT, class F>
__device__ __forceinline__ void job_gemm(double* __restrict__ As,
                                         float* __restrict__ Ws,
                                         const AT* __restrict__ A, long lda,
                                         const float* __restrict__ W, int ldw,
                                         int n_off, F f) {
  const int tid = threadIdx.x;
  const int c0 = (tid & 15) * 2;
  const int r0 = (tid >> 4) * 2;
  const int ar = tid >> 3;                 // A stage row 0..31
  const int ak = (tid & 7) * 8;            // A stage k base
  const int wn = tid & 31;                 // W stage col
  const int wk = tid >> 5;                 // W stage row base (8 rows/pass)

  double aReg[8];
  float  wReg[8];
  {
    const AT* Ap = A + (size_t)ar * lda + ak;
#pragma unroll
    for (int i = 0; i < 8; ++i) aReg[i] = (double)Ap[i];
    const float* Wp = W + (size_t)wk * ldw + n_off + wn;
#pragma unroll
    for (int p = 0; p < 8; ++p) wReg[p] = Wp[(size_t)p * 8 * ldw];
  }
  double acc[2][2];
  acc[0][0] = acc[0][1] = acc[1][0] = acc[1][1] = 0.0;

  for (int k0 = 0; k0 < 1024; k0 += 64) {
#pragma unroll
    for (int i = 0; i < 8; ++i) As[ar * 65 + ak + i] = aReg[i];
#pragma unroll
    for (int p = 0; p < 8; ++p) Ws[(wk + p * 8) * 36 + wn] = wReg[p];
    __syncthreads();
    if (k0 + 64 < 1024) {                  // prefetch next chunk into regs
      const AT* Ap = A + (size_t)ar * lda + (k0 + 64) + ak;
#pragma unroll
      for (int i = 0; i < 8; ++i) aReg[i] = (double)Ap[i];
      const float* Wp = W + (size_t)(k0 + 64 + wk) * ldw + n_off + wn;
#pragma unroll
      for (int p = 0; p < 8; ++p) wReg[p] = Wp[(size_t)p * 8 * ldw];
    }
#pragma unroll
    for (int kk = 0; kk < 64; ++kk) {
      double a0 = As[r0 * 65 + kk], a1 = As[(r0 + 1) * 65 + kk];
      double w0 = (double)Ws[kk * 36 + c0], w1 = (double)Ws[kk * 36 + c0 + 1];
      acc[0][0] = fma(a0, w0, acc[0][0]);
      acc[0][1] = fma(a0, w1, acc[0][1]);
      acc[1][0] = fma(a1, w0, acc[1][0]);
      acc[1][1] = fma(a1, w1, acc[1][1]);
    }
    __syncthreads();
  }
#pragma unroll
  for (int i = 0; i < 2; ++i)
#pragma unroll
    for (int j = 0; j < 2; ++j) f(r0 + i, c0 + j, acc[i][j]);
}

// ---- init: fp64 master state + tanh copy; zero barrier state ----
__global__ __launch_bounds__(256) void k_init(const float* __restrict__ memory,
                                              double* __restrict__ mem,
                                              double* __restrict__ tmem,
                                              unsigned* __restrict__ cnt,
                                              unsigned* __restrict__ gen, int n) {
  int i = blockIdx.x * 256 + threadIdx.x;
  if (i == 0) { *cnt = 0u; *gen = 0u; }
  if (i >= n) return;
  double v = (double)memory[i];
  mem[i] = v; tmem[i] = tanh(v);
}

// ---------------------------------------------------------------------------
// The fused persistent kernel: full T-loop, 5 phases per step, gsync between.
// ---------------------------------------------------------------------------
__global__ __launch_bounds__(256) void k_fused(
    const float* __restrict__ inputs,
    const float* __restrict__ Wq, const float* __restrict__ Wk,
    const float* __restrict__ Wv, const float* __restrict__ Wo,
    const float* __restrict__ W1, const float* __restrict__ W2,
    const float* __restrict__ Wg, const float* __restrict__ Ug,
    const float* __restrict__ bq, const float* __restrict__ bk,
    const float* __restrict__ bv, const float* __restrict__ bo,
    const float* __restrict__ b1, const float* __restrict__ b2,
    const float* __restrict__ bg, const float* __restrict__ bu,
    double* __restrict__ mem, double* __restrict__ tmem,
    double* __restrict__ nm, double* __restrict__ o, double* __restrict__ h1,
    float* __restrict__ q, float* __restrict__ km, float* __restrict__ vm,
    float* __restrict__ g, float* __restrict__ kx, float* __restrict__ vx,
    float* __restrict__ xg,
    unsigned* __restrict__ cnt, unsigned* __restrict__ gen,
    float* __restrict__ out) {
  __shared__ double As[32 * 65];
  __shared__ float  Ws[64 * 36];
  const int blk = blockIdx.x;
  const int tid = threadIdx.x;

  for (int t = 0; t < T_; ++t) {
    // ---------------- phase A: qkvg (960 jobs) + prex (256 jobs) ----------
    for (int j = blk; j < 1216; j += NBLK) {
      if (j < 960) {
        int ct = j / 6, rt = j % 6;
        int cb = ct * 32, rb = rt * 32;
        const double* Asrc = ((cb < 3072) ? mem : tmem) + (size_t)rb * 1024;
        const float* W; int ldw, n_off;
        if      (cb < 1024) { W = Wq; ldw = 1024; n_off = cb; }
        else if (cb < 2048) { W = Wk; ldw = 1024; n_off = cb - 1024; }
        else if (cb < 3072) { W = Wv; ldw = 1024; n_off = cb - 2048; }
        else                { W = Ug; ldw = 2048; n_off = cb - 3072; }
        job_gemm(As, Ws, Asrc, 1024L, W, ldw, n_off,
                 [&](int r, int c, double v) {
          int row = rb + r, col = cb + c;
          if (col < 1024)      q [(size_t)row * 1024 + col]        = (float)(v + (double)bq[col]);
          else if (col < 2048) km[(size_t)row * 1024 + col - 1024] = (float)(v + (double)bk[col - 1024]);
          else if (col < 3072) vm[(size_t)row * 1024 + col - 2048] = (float)(v + (double)bv[col - 2048]);
          else                 g [(size_t)row * 2048 + col - 3072] = (float)v;
        });
      } else {
        int pb = j - 960;
        int ct = pb / 2, rt = pb % 2;
        int cb = ct * 32, rb = rt * 32;
        const float* Asrc = inputs + (size_t)rb * (T_ * 1024) + (size_t)t * 1024;
        const float* W; int ldw, n_off;
        if      (cb < 1024) { W = Wk; ldw = 1024; n_off = cb; }
        else if (cb < 2048) { W = Wv; ldw = 1024; n_off = cb - 1024; }
        else                { W = Wg; ldw = 2048; n_off = cb - 2048; }
        job_gemm(As, Ws, Asrc, (long)T_ * 1024, W, ldw, n_off,
                 [&](int r, int c, double v) {
          int b = rb + r, col = cb + c;
          if (col < 1024)      kx[(size_t)b * 1024 + col]        = (float)(v + (double)bk[col]);
          else if (col < 2048) vx[(size_t)b * 1024 + col - 1024] = (float)(v + (double)bv[col - 1024]);
          else { int jj = col - 2048; xg[(size_t)b * 2048 + jj] = (float)(v + (double)bg[jj] + (double)bu[jj]); }
        });
      }
    }
    gsync(cnt, gen);

    // ---------------- phase B: attention (512 wave-jobs on blocks 0..127) --
    if (blk < 128) {
      int bh = blk * 4 + (tid >> 6);
      int b = bh >> 3, h = bh & 7;
      int lane = tid & 63;
      int col = h * 128 + lane;
      double q0[3], q1[3], kk0[4], kk1[4], vv0[4], vv1[4];
#pragma unroll
      for (int s = 0; s < 3; ++s) {
        size_t r = (size_t)(b * 3 + s) * 1024 + col;
        q0[s] = (double)q[r]; q1[s] = (double)q[r + 64];
      }
#pragma unroll
      for (int j = 0; j < 3; ++j) {
        size_t r = (size_t)(b * 3 + j) * 1024 + col;
        kk0[j] = (double)km[r]; kk1[j] = (double)km[r + 64];
        vv0[j] = (double)vm[r]; vv1[j] = (double)vm[r + 64];
      }
      {
        size_t r = (size_t)b * 1024 + col;
        kk0[3] = (double)kx[r]; kk1[3] = (double)kx[r + 64];
        vv0[3] = (double)vx[r]; vv1[3] = (double)vx[r + 64];
      }
      const double scale = 0.08838834764831845;  // 1/sqrt(128)
      double p[3][4];
#pragma unroll
      for (int s = 0; s < 3; ++s)
#pragma unroll
        for (int j = 0; j < 4; ++j) {
          double d = q0[s] * kk0[j] + q1[s] * kk1[j];
#pragma unroll
          for (int off = 32; off > 0; off >>= 1) d += __shfl_xor(d, off);
          p[s][j] = d * scale;
        }
#pragma unroll
      for (int s = 0; s < 3; ++s) {
        double m = fmax(fmax(p[s][0], p[s][1]), fmax(p[s][2], p[s][3]));
        double e0 = exp(p[s][0] - m), e1 = exp(p[s][1] - m);
        double e2 = exp(p[s][2] - m), e3 = exp(p[s][3] - m);
        double inv = 1.0 / (e0 + e1 + e2 + e3);
        double o0 = (e0 * vv0[0] + e1 * vv0[1] + e2 * vv0[2] + e3 * vv0[3]) * inv;
        double o1 = (e0 * vv1[0] + e1 * vv1[1] + e2 * vv1[2] + e3 * vv1[3]) * inv;
        size_t r = (size_t)(b * 3 + s) * 1024 + col;
        o[r] = o0; o[r + 64] = o1;
      }
    }
    gsync(cnt, gen);

    // ---------------- phase C: nm = mem + o@Wo + bo (192 jobs) -------------
    if (blk < 192) {
      int ct = blk / 6, rt = blk % 6;
      int cb = ct * 32, rb = rt * 32;
      job_gemm(As, Ws, o + (size_t)rb * 1024, 1024L, Wo, 1024, cb,
               [&](int r, int c, double v) {
        size_t idx = (size_t)(rb + r) * 1024 + cb + c;
        nm[idx] = mem[idx] + v + (double)bo[cb + c];
      });
    }
    gsync(cnt, gen);

    // ---------------- phase D: h1 = relu(nm@W1 + b1) (192 jobs) ------------
    if (blk < 192) {
      int ct = blk / 6, rt = blk % 6;
      int cb = ct * 32, rb = rt * 32;
      job_gemm(As, Ws, nm + (size_t)rb * 1024, 1024L, W1, 1024, cb,
               [&](int r, int c, double v) {
        h1[(size_t)(rb + r) * 1024 + cb + c] = fmax(v + (double)b1[cb + c], 0.0);
      });
    }
    gsync(cnt, gen);

    // ---------------- phase E: ff2 + gate + state update (192 jobs) --------
    if (blk < 192) {
      int ct = blk / 6, rt = blk % 6;
      int cb = ct * 32, rb = rt * 32;
      job_gemm(As, Ws, h1 + (size_t)rb * 1024, 1024L, W2, 1024, cb,
               [&](int r, int c, double v) {
        int row = rb + r, col = cb + c;
        size_t idx = (size_t)row * 1024 + col;
        double ml = fmax(v + (double)b2[col], 0.0);
        double nm2 = nm[idx] + ml;
        int b = row / 3;
        int s = row - b * 3;
        double ig = (double)xg[(size_t)b * 2048 + col]        + (double)g[(size_t)row * 2048 + col];
        double fg = (double)xg[(size_t)b * 2048 + 1024 + col] + (double)g[(size_t)row * 2048 + 1024 + col];
        double old = mem[idx];
        double nv = sigm_d(ig) * tanh(nm2) + sigm_d(fg) * old;
        out[(size_t)(b * T_ + t) * 3072 + s * 1024 + col] = (float)nv;
        mem[idx]  = nv;
        tmem[idx] = tanh(nv);
      });
    }
    gsync(cnt, gen);
  }
}

// ---------------------------------------------------------------------------
extern "C" void kernel_launch(void* const* d_in, const int* in_sizes, int n_in,
                              void* d_out, int out_size, void* d_ws, size_t ws_size,
                              hipStream_t stream) {
  (void)in_sizes; (void)n_in; (void)out_size;
  const float* inputs = (const float*)d_in[0];
  const float* memory = (const float*)d_in[1];
  const float* Wq = (const float*)d_in[2];  const float* bq = (const float*)d_in[3];
  const float* Wk = (const float*)d_in[4];  const float* bk = (const float*)d_in[5];
  const float* Wv = (const float*)d_in[6];  const float* bv = (const float*)d_in[7];
  const float* Wo = (const float*)d_in[8];  const float* bo = (const float*)d_in[9];
  const float* W1 = (const float*)d_in[10]; const float* b1 = (const float*)d_in[11];
  const float* W2 = (const float*)d_in[12]; const float* b2 = (const float*)d_in[13];
  const float* Wg = (const float*)d_in[14]; const float* bg = (const float*)d_in[15];
  const float* Ug = (const float*)d_in[16]; const float* bu = (const float*)d_in[17];
  float* out = (float*)d_out;

  // Footprint ~12.6 MB (ws = 64 MiB). Bail-signature if wrong: absmax 4.3125.
  if (ws_size < (size_t)16 * 1024 * 1024) return;

  char* ws = (char*)d_ws;
  size_t off = 0;
  auto alloc = [&](size_t bytes) -> void* {
    void* p = ws + off; off += (bytes + 255) & ~(size_t)255; return p;
  };
  unsigned* cnt = (unsigned*)alloc(256);     // barrier counter (own slot)
  unsigned* gen = (unsigned*)alloc(256);     // generation word (own slot -- was
                                             // aliasing mem[0] in R10!)
  double* mem  = (double*)alloc((size_t)196608 * 8);
  double* tmem = (double*)alloc((size_t)196608 * 8);
  double* nm   = (double*)alloc((size_t)196608 * 8);
  double* o    = (double*)alloc((size_t)196608 * 8);
  double* h1   = (double*)alloc((size_t)196608 * 8);
  float* q  = (float*)alloc((size_t)196608 * 4);
  float* km = (float*)alloc((size_t)196608 * 4);
  float* vm = (float*)alloc((size_t)196608 * 4);
  float* g  = (float*)alloc((size_t)192 * 2048 * 4);
  float* kx = (float*)alloc((size_t)64 * 1024 * 4);
  float* vx = (float*)alloc((size_t)64 * 1024 * 4);
  float* xg = (float*)alloc((size_t)64 * 2048 * 4);

  k_init<<<768, 256, 0, stream>>>(memory, mem, tmem, cnt, gen, 196608);
  k_fused<<<NBLK, 256, 0, stream>>>(inputs, Wq, Wk, Wv, Wo, W1, W2, Wg, Ug,
                                    bq, bk, bv, bo, b1, b2, bg, bu,
                                    mem, tmem, nm, o, h1,
                                    q, km, vm, g, kx, vx, xg, cnt, gen, out);
}

// Round 12
// 53569.763 us; speedup vs baseline: 1.3592x; 1.3592x over previous
//
// R12: persistent kernel, barrier de-pollution round. R11 diagnosis (rocprof):
// VALUBusy 14%, FETCH 18.4GB (weights refetched 3.6x/step) -- every thread's
// __threadfence + every ACQUIRE poll invalidated the XCD L2 mid-phase.
// Changes: (1) leader-only fence after __syncthreads (block stores already
// >=L2 at barrier); (2) RELAXED spin polls + single ACQUIRE after exit;
// (3) NBLK=512, 2 blocks/CU (__launch_bounds__(256,2)) for TLP.
// Phases/math unchanged -> output bit-identical (absmax 0.015625).
#include <hip/hip_runtime.h>
#include <math.h>

#define T_ 128
#define NBLK 512

__device__ __forceinline__ double sigm_d(double x) { return 1.0 / (1.0 + exp(-x)); }

// ---- software grid barrier, cache-friendly ----
// release: __syncthreads (drains each wave's stores to >=L2) + leader-only
// __threadfence (L2 writeback) + ACQ_REL RMW.
// spin: RELAXED loads (coherent-point read, NO cache invalidate per poll);
// one ACQUIRE load after exit supplies the invalidate exactly once.
__device__ __forceinline__ void gsync(unsigned* cnt, unsigned* gen) {
  __syncthreads();
  if (threadIdx.x == 0) {
    __threadfence();   // publish this block's (already-in-L2) stores device-wide
    unsigned g = __hip_atomic_load(gen, __ATOMIC_RELAXED, __HIP_MEMORY_SCOPE_AGENT);
    unsigned a = __hip_atomic_fetch_add(cnt, 1u, __ATOMIC_ACQ_REL, __HIP_MEMORY_SCOPE_AGENT);
    if (a == NBLK - 1u) {
      // cnt reset is release-ordered before the gen bump
      __hip_atomic_store(cnt, 0u, __ATOMIC_RELAXED, __HIP_MEMORY_SCOPE_AGENT);
      __hip_atomic_store(gen, g + 1u, __ATOMIC_RELEASE, __HIP_MEMORY_SCOPE_AGENT);
      // acquire side for this block came from the ACQ_REL RMW (it was last)
    } else {
      while (__hip_atomic_load(gen, __ATOMIC_RELAXED, __HIP_MEMORY_SCOPE_AGENT) == g)
        __builtin_amdgcn_s_sleep(2);
      (void)__hip_atomic_load(gen, __ATOMIC_ACQUIRE, __HIP_MEMORY_SCOPE_AGENT);
    }
  }
  __syncthreads();
}

// ---------------------------------------------------------------------------
// 32x32-tile GEMM job with register-prefetch staging:
// C_tile[32x32] = A[32 rows][0:1024] x W[0:1024][n_off:+32]
// A: AT* (double/float, row stride lda) -> fp64 LDS As[32][65].
// W: fp32 [1024][ldw] -> fp32 LDS Ws[64][36], cvt at use.
// ---------------------------------------------------------------------------
template<typename AT, class F>
__device__ __forceinline__ void job_gemm(double* __restrict__ As,
                                         float* __restrict__ Ws,
                                         const AT* __restrict__ A, long lda,
                                         const float* __restrict__ W, int ldw,
                                         int n_off, F f) {
  const int tid = threadIdx.x;
  const int c0 = (tid & 15) * 2;
  const int r0 = (tid >> 4) * 2;
  const int ar = tid >> 3;                 // A stage row 0..31
  const int ak = (tid & 7) * 8;            // A stage k base
  const int wn = tid & 31;                 // W stage col
  const int wk = tid >> 5;                 // W stage row base (8 rows/pass)

  double aReg[8];
  float  wReg[8];
  {
    const AT* Ap = A + (size_t)ar * lda + ak;
#pragma unroll
    for (int i = 0; i < 8; ++i) aReg[i] = (double)Ap[i];
    const float* Wp = W + (size_t)wk * ldw + n_off + wn;
#pragma unroll
    for (int p = 0; p < 8; ++p) wReg[p] = Wp[(size_t)p * 8 * ldw];
  }
  double acc[2][2];
  acc[0][0] = acc[0][1] = acc[1][0] = acc[1][1] = 0.0;

  for (int k0 = 0; k0 < 1024; k0 += 64) {
#pragma unroll
    for (int i = 0; i < 8; ++i) As[ar * 65 + ak + i] = aReg[i];
#pragma unroll
    for (int p = 0; p < 8; ++p) Ws[(wk + p * 8) * 36 + wn] = wReg[p];
    __syncthreads();
    if (k0 + 64 < 1024) {                  // prefetch next chunk into regs
      const AT* Ap = A + (size_t)ar * lda + (k0 + 64) + ak;
#pragma unroll
      for (int i = 0; i < 8; ++i) aReg[i] = (double)Ap[i];
      const float* Wp = W + (size_t)(k0 + 64 + wk) * ldw + n_off + wn;
#pragma unroll
      for (int p = 0; p < 8; ++p) wReg[p] = Wp[(size_t)p * 8 * ldw];
    }
#pragma unroll
    for (int kk = 0; kk < 64; ++kk) {
      double a0 = As[r0 * 65 + kk], a1 = As[(r0 + 1) * 65 + kk];
      double w0 = (double)Ws[kk * 36 + c0], w1 = (double)Ws[kk * 36 + c0 + 1];
      acc[0][0] = fma(a0, w0, acc[0][0]);
      acc[0][1] = fma(a0, w1, acc[0][1]);
      acc[1][0] = fma(a1, w0, acc[1][0]);
      acc[1][1] = fma(a1, w1, acc[1][1]);
    }
    __syncthreads();
  }
#pragma unroll
  for (int i = 0; i < 2; ++i)
#pragma unroll
    for (int j = 0; j < 2; ++j) f(r0 + i, c0 + j, acc[i][j]);
}

// ---- init: fp64 master state + tanh copy; zero barrier state ----
__global__ __launch_bounds__(256) void k_init(const float* __restrict__ memory,
                                              double* __restrict__ mem,
                                              double* __restrict__ tmem,
                                              unsigned* __restrict__ cnt,
                                              unsigned* __restrict__ gen, int n) {
  int i = blockIdx.x * 256 + threadIdx.x;
  if (i == 0) { *cnt = 0u; *gen = 0u; }
  if (i >= n) return;
  double v = (double)memory[i];
  mem[i] = v; tmem[i] = tanh(v);
}

// ---------------------------------------------------------------------------
// The fused persistent kernel: full T-loop, 5 phases per step, gsync between.
// ---------------------------------------------------------------------------
__global__ __launch_bounds__(256, 2) void k_fused(
    const float* __restrict__ inputs,
    const float* __restrict__ Wq, const float* __restrict__ Wk,
    const float* __restrict__ Wv, const float* __restrict__ Wo,
    const float* __restrict__ W1, const float* __restrict__ W2,
    const float* __restrict__ Wg, const float* __restrict__ Ug,
    const float* __restrict__ bq, const float* __restrict__ bk,
    const float* __restrict__ bv, const float* __restrict__ bo,
    const float* __restrict__ b1, const float* __restrict__ b2,
    const float* __restrict__ bg, const float* __restrict__ bu,
    double* __restrict__ mem, double* __restrict__ tmem,
    double* __restrict__ nm, double* __restrict__ o, double* __restrict__ h1,
    float* __restrict__ q, float* __restrict__ km, float* __restrict__ vm,
    float* __restrict__ g, float* __restrict__ kx, float* __restrict__ vx,
    float* __restrict__ xg,
    unsigned* __restrict__ cnt, unsigned* __restrict__ gen,
    float* __restrict__ out) {
  __shared__ double As[32 * 65];
  __shared__ float  Ws[64 * 36];
  const int blk = blockIdx.x;
  const int tid = threadIdx.x;

  for (int t = 0; t < T_; ++t) {
    // ---------------- phase A: qkvg (960 jobs) + prex (256 jobs) ----------
    for (int j = blk; j < 1216; j += NBLK) {
      if (j < 960) {
        int ct = j / 6, rt = j % 6;
        int cb = ct * 32, rb = rt * 32;
        const double* Asrc = ((cb < 3072) ? mem : tmem) + (size_t)rb * 1024;
        const float* W; int ldw, n_off;
        if      (cb < 1024) { W = Wq; ldw = 1024; n_off = cb; }
        else if (cb < 2048) { W = Wk; ldw = 1024; n_off = cb - 1024; }
        else if (cb < 3072) { W = Wv; ldw = 1024; n_off = cb - 2048; }
        else                { W = Ug; ldw = 2048; n_off = cb - 3072; }
        job_gemm(As, Ws, Asrc, 1024L, W, ldw, n_off,
                 [&](int r, int c, double v) {
          int row = rb + r, col = cb + c;
          if (col < 1024)      q [(size_t)row * 1024 + col]        = (float)(v + (double)bq[col]);
          else if (col < 2048) km[(size_t)row * 1024 + col - 1024] = (float)(v + (double)bk[col - 1024]);
          else if (col < 3072) vm[(size_t)row * 1024 + col - 2048] = (float)(v + (double)bv[col - 2048]);
          else                 g [(size_t)row * 2048 + col - 3072] = (float)v;
        });
      } else {
        int pb = j - 960;
        int ct = pb / 2, rt = pb % 2;
        int cb = ct * 32, rb = rt * 32;
        const float* Asrc = inputs + (size_t)rb * (T_ * 1024) + (size_t)t * 1024;
        const float* W; int ldw, n_off;
        if      (cb < 1024) { W = Wk; ldw = 1024; n_off = cb; }
        else if (cb < 2048) { W = Wv; ldw = 1024; n_off = cb - 1024; }
        else                { W = Wg; ldw = 2048; n_off = cb - 2048; }
        job_gemm(As, Ws, Asrc, (long)T_ * 1024, W, ldw, n_off,
                 [&](int r, int c, double v) {
          int b = rb + r, col = cb + c;
          if (col < 1024)      kx[(size_t)b * 1024 + col]        = (float)(v + (double)bk[col]);
          else if (col < 2048) vx[(size_t)b * 1024 + col - 1024] = (float)(v + (double)bv[col - 1024]);
          else { int jj = col - 2048; xg[(size_t)b * 2048 + jj] = (float)(v + (double)bg[jj] + (double)bu[jj]); }
        });
      }
    }
    gsync(cnt, gen);

    // ---------------- phase B: attention (512 wave-jobs on blocks 0..127) --
    if (blk < 128) {
      int bh = blk * 4 + (tid >> 6);
      int b = bh >> 3, h = bh & 7;
      int lane = tid & 63;
      int col = h * 128 + lane;
      double q0[3], q1[3], kk0[4], kk1[4], vv0[4], vv1[4];
#pragma unroll
      for (int s = 0; s < 3; ++s) {
        size_t r = (size_t)(b * 3 + s) * 1024 + col;
        q0[s] = (double)q[r]; q1[s] = (double)q[r + 64];
      }
#pragma unroll
      for (int j = 0; j < 3; ++j) {
        size_t r = (size_t)(b * 3 + j) * 1024 + col;
        kk0[j] = (double)km[r]; kk1[j] = (double)km[r + 64];
        vv0[j] = (double)vm[r]; vv1[j] = (double)vm[r + 64];
      }
      {
        size_t r = (size_t)b * 1024 + col;
        kk0[3] = (double)kx[r]; kk1[3] = (double)kx[r + 64];
        vv0[3] = (double)vx[r]; vv1[3] = (double)vx[r + 64];
      }
      const double scale = 0.08838834764831845;  // 1/sqrt(128)
      double p[3][4];
#pragma unroll
      for (int s = 0; s < 3; ++s)
#pragma unroll
        for (int j = 0; j < 4; ++j) {
          double d = q0[s] * kk0[j] + q1[s] * kk1[j];
#pragma unroll
          for (int off = 32; off > 0; off >>= 1) d += __shfl_xor(d, off);
          p[s][j] = d * scale;
        }
#pragma unroll
      for (int s = 0; s < 3; ++s) {
        double m = fmax(fmax(p[s][0], p[s][1]), fmax(p[s][2], p[s][3]));
        double e0 = exp(p[s][0] - m), e1 = exp(p[s][1] - m);
        double e2 = exp(p[s][2] - m), e3 = exp(p[s][3] - m);
        double inv = 1.0 / (e0 + e1 + e2 + e3);
        double o0 = (e0 * vv0[0] + e1 * vv0[1] + e2 * vv0[2] + e3 * vv0[3]) * inv;
        double o1 = (e0 * vv1[0] + e1 * vv1[1] + e2 * vv1[2] + e3 * vv1[3]) * inv;
        size_t r = (size_t)(b * 3 + s) * 1024 + col;
        o[r] = o0; o[r + 64] = o1;
      }
    }
    gsync(cnt, gen);

    // ---------------- phase C: nm = mem + o@Wo + bo (192 jobs) -------------
    if (blk < 192) {
      int ct = blk / 6, rt = blk % 6;
      int cb = ct * 32, rb = rt * 32;
      job_gemm(As, Ws, o + (size_t)rb * 1024, 1024L, Wo, 1024, cb,
               [&](int r, int c, double v) {
        size_t idx = (size_t)(rb + r) * 1024 + cb + c;
        nm[idx] = mem[idx] + v + (double)bo[cb + c];
      });
    }
    gsync(cnt, gen);

    // ---------------- phase D: h1 = relu(nm@W1 + b1) (192 jobs) ------------
    if (blk < 192) {
      int ct = blk / 6, rt = blk % 6;
      int cb = ct * 32, rb = rt * 32;
      job_gemm(As, Ws, nm + (size_t)rb * 1024, 1024L, W1, 1024, cb,
               [&](int r, int c, double v) {
        h1[(size_t)(rb + r) * 1024 + cb + c] = fmax(v + (double)b1[cb + c], 0.0);
      });
    }
    gsync(cnt, gen);

    // ---------------- phase E: ff2 + gate + state update (192 jobs) --------
    if (blk < 192) {
      int ct = blk / 6, rt = blk % 6;
      int cb = ct * 32, rb = rt * 32;
      job_gemm(As, Ws, h1 + (size_t)rb * 1024, 1024L, W2, 1024, cb,
               [&](int r, int c, double v) {
        int row = rb + r, col = cb + c;
        size_t idx = (size_t)row * 1024 + col;
        double ml = fmax(v + (double)b2[col], 0.0);
        double nm2 = nm[idx] + ml;
        int b = row / 3;
        int s = row - b * 3;
        double ig = (double)xg[(size_t)b * 2048 + col]        + (double)g[(size_t)row * 2048 + col];
        double fg = (double)xg[(size_t)b * 2048 + 1024 + col] + (double)g[(size_t)row * 2048 + 1024 + col];
        double old = mem[idx];
        double nv = sigm_d(ig) * tanh(nm2) + sigm_d(fg) * old;
        out[(size_t)(b * T_ + t) * 3072 + s * 1024 + col] = (float)nv;
        mem[idx]  = nv;
        tmem[idx] = tanh(nv);
      });
    }
    gsync(cnt, gen);
  }
}

// ---------------------------------------------------------------------------
extern "C" void kernel_launch(void* const* d_in, const int* in_sizes, int n_in,
                              void* d_out, int out_size, void* d_ws, size_t ws_size,
                              hipStream_t stream) {
  (void)in_sizes; (void)n_in; (void)out_size;
  const float* inputs = (const float*)d_in[0];
  const float* memory = (const float*)d_in[1];
  const float* Wq = (const float*)d_in[2];  const float* bq = (const float*)d_in[3];
  const float* Wk = (const float*)d_in[4];  const float* bk = (const float*)d_in[5];
  const float* Wv = (const float*)d_in[6];  const float* bv = (const float*)d_in[7];
  const float* Wo = (const float*)d_in[8];  const float* bo = (const float*)d_in[9];
  const float* W1 = (const float*)d_in[10]; const float* b1 = (const float*)d_in[11];
  const float* W2 = (const float*)d_in[12]; const float* b2 = (const float*)d_in[13];
  const float* Wg = (const float*)d_in[14]; const float* bg = (const float*)d_in[15];
  const float* Ug = (const float*)d_in[16]; const float* bu = (const float*)d_in[17];
  float* out = (float*)d_out;

  // Footprint ~12.6 MB (ws = 64 MiB). Bail-signature if wrong: absmax 4.3125.
  if (ws_size < (size_t)16 * 1024 * 1024) return;

  char* ws = (char*)d_ws;
  size_t off = 0;
  auto alloc = [&](size_t bytes) -> void* {
    void* p = ws + off; off += (bytes + 255) & ~(size_t)255; return p;
  };
  unsigned* cnt = (unsigned*)alloc(256);     // barrier counter (own slot)
  unsigned* gen = (unsigned*)alloc(256);     // generation word (own slot)
  double* mem  = (double*)alloc((size_t)196608 * 8);
  double* tmem = (double*)alloc((size_t)196608 * 8);
  double* nm   = (double*)alloc((size_t)196608 * 8);
  double* o    = (double*)alloc((size_t)196608 * 8);
  double* h1   = (double*)alloc((size_t)196608 * 8);
  float* q  = (float*)alloc((size_t)196608 * 4);
  float* km = (float*)alloc((size_t)196608 * 4);
  float* vm = (float*)alloc((size_t)196608 * 4);
  float* g  = (float*)alloc((size_t)192 * 2048 * 4);
  float* kx = (float*)alloc((size_t)64 * 1024 * 4);
  float* vx = (float*)alloc((size_t)64 * 1024 * 4);
  float* xg = (float*)alloc((size_t)64 * 2048 * 4);

  k_init<<<768, 256, 0, stream>>>(memory, mem, tmem, cnt, gen, 196608);
  k_fused<<<NBLK, 256, 0, stream>>>(inputs, Wq, Wk, Wv, Wo, W1, W2, Wg, Ug,
                                    bq, bk, bv, bo, b1, b2, bg, bu,
                                    mem, tmem, nm, o, h1,
                                    q, km, vm, g, kx, vx, xg, cnt, gen, out);
}

// Round 13
// 47624.411 us; speedup vs baseline: 1.5289x; 1.1248x over previous
//
// R13: persistent kernel with LDS-RESIDENT WEIGHTS. Diagnosis (R11/R12 PMC):
// every phase boundary (sw barrier OR kernel launch) invalidates per-XCD L2,
// evicting the 40MB weight set -> refetched from LLC each phase (FETCH 17.8GB,
// VALUBusy 20%). Fix: 40MB fp32 weights == 256 CUs x 160KB LDS exactly.
// One block/CU holds 4 cols of each square W + 8 of Wg/Ug in LDS (XOR-swizzled,
// bank-disjoint b128 reads) for the whole T-loop; barriers can no longer evict
// them. A-operands stream as fp32 via L2 (state master fp64, fp64 accumulate,
// same serial-k order -- input fp32 rounding is sqrt(K)-scaled, ~30x below the
// accumulation error that set the 0.109 failure in R5).
#include <hip/hip_runtime.h>
#include <math.h>

#define T_ 128
#define NBLK 256
#define NTHR 1024

__device__ __forceinline__ double sigm_d(double x) { return 1.0 / (1.0 + exp(-x)); }

// ---- software grid barrier (R12's proven version, NBLK participants) ----
__device__ __forceinline__ void gsync(unsigned* cnt, unsigned* gen) {
  __syncthreads();
  if (threadIdx.x == 0) {
    __threadfence();
    unsigned g = __hip_atomic_load(gen, __ATOMIC_RELAXED, __HIP_MEMORY_SCOPE_AGENT);
    unsigned a = __hip_atomic_fetch_add(cnt, 1u, __ATOMIC_ACQ_REL, __HIP_MEMORY_SCOPE_AGENT);
    if (a == NBLK - 1u) {
      __hip_atomic_store(cnt, 0u, __ATOMIC_RELAXED, __HIP_MEMORY_SCOPE_AGENT);
      __hip_atomic_store(gen, g + 1u, __ATOMIC_RELEASE, __HIP_MEMORY_SCOPE_AGENT);
    } else {
      while (__hip_atomic_load(gen, __ATOMIC_RELAXED, __HIP_MEMORY_SCOPE_AGENT) == g)
        __builtin_amdgcn_s_sleep(2);
      (void)__hip_atomic_load(gen, __ATOMIC_ACQUIRE, __HIP_MEMORY_SCOPE_AGENT);
    }
  }
  __syncthreads();
}

// ---- serial-k fp64 dot: A_f32 row (global, L2) x LDS weight col (swizzled) ----
// Swizzle: float index = base + j*1024 + ((k & ~31) | ((k & 31) ^ ((j&3)<<3)))
// -> the 4 cols j=0..3 read bank-disjoint 16B chunks (j&3 repeats for 8-col
// mats: 2-way conflict, which is free).
__device__ __forceinline__ double dotWL(const float* __restrict__ Ap,
                                        const float* __restrict__ Wp, int rot) {
  double acc = 0.0;
#pragma unroll 8
  for (int k = 0; k < 1024; k += 4) {
    float4 a = *(const float4*)(Ap + k);
    float4 w = *(const float4*)(Wp + ((k & ~31) | ((k & 31) ^ rot)));
    acc = fma((double)a.x, (double)w.x, acc);
    acc = fma((double)a.y, (double)w.y, acc);
    acc = fma((double)a.z, (double)w.z, acc);
    acc = fma((double)a.w, (double)w.w, acc);
  }
  return acc;
}

// ---- stage one weight slice (ncol cols starting col0) into LDS, swizzled ----
__device__ __forceinline__ void loadW(const float* __restrict__ G, int ldw,
                                      int col0, int ncol, float* __restrict__ dst) {
  for (int i = threadIdx.x; i < (ncol << 10); i += NTHR) {
    int j = i >> 10, k = i & 1023;
    dst[j * 1024 + ((k & ~31) | ((k & 31) ^ ((j & 3) << 3)))] =
        G[(size_t)k * ldw + col0 + j];
  }
}

// ---- init: fp64 master + fp32 copies; zero barrier words ----
__global__ __launch_bounds__(256) void k_init(const float* __restrict__ memory,
                                              double* __restrict__ mem64,
                                              float* __restrict__ mem32,
                                              float* __restrict__ tmem32,
                                              unsigned* __restrict__ cnt,
                                              unsigned* __restrict__ gen, int n) {
  int i = blockIdx.x * 256 + threadIdx.x;
  if (i == 0) { *cnt = 0u; *gen = 0u; }
  if (i >= n) return;
  double v = (double)memory[i];
  mem64[i] = v; mem32[i] = (float)v; tmem32[i] = (float)tanh(v);
}

// ---------------------------------------------------------------------------
// Persistent fused kernel. LDS layout (floats):
// Wq 0 | Wk 4096 | Wv 8192 | Wo 12288 | W1 16384 | W2 20480 |
// Ug 24576 (8 cols) | Wg 32768 (8 cols)  -> 40960 floats = 160 KiB exactly.
// Block bid owns square-mat cols [4b,4b+4) and wide-mat cols [8b,8b+8).
// ---------------------------------------------------------------------------
__global__ __launch_bounds__(NTHR) void k_fused(
    const float* __restrict__ inputs,
    const float* __restrict__ Wq, const float* __restrict__ Wk,
    const float* __restrict__ Wv, const float* __restrict__ Wo,
    const float* __restrict__ W1, const float* __restrict__ W2,
    const float* __restrict__ Wg, const float* __restrict__ Ug,
    const float* __restrict__ bq, const float* __restrict__ bk,
    const float* __restrict__ bv, const float* __restrict__ bo,
    const float* __restrict__ b1, const float* __restrict__ b2,
    const float* __restrict__ bg, const float* __restrict__ bu,
    double* __restrict__ mem64, double* __restrict__ nm64,
    float* __restrict__ mem32, float* __restrict__ tmem32,
    float* __restrict__ nm32, float* __restrict__ o32,
    float* __restrict__ h132, float* __restrict__ q32,
    float* __restrict__ km32, float* __restrict__ vm32,
    float* __restrict__ g32, float* __restrict__ kx32,
    float* __restrict__ vx32, float* __restrict__ xg32,
    unsigned* __restrict__ cnt, unsigned* __restrict__ gen,
    float* __restrict__ out) {
  __shared__ float WL[40960];          // 160 KiB: this CU's weight slice
  const int bid = blockIdx.x, tid = threadIdx.x;
  const int cq = bid * 4;              // square-mat col base
  const int cw = bid * 8;              // wide-mat col base

  loadW(Wq, 1024, cq, 4, WL + 0);
  loadW(Wk, 1024, cq, 4, WL + 4096);
  loadW(Wv, 1024, cq, 4, WL + 8192);
  loadW(Wo, 1024, cq, 4, WL + 12288);
  loadW(W1, 1024, cq, 4, WL + 16384);
  loadW(W2, 1024, cq, 4, WL + 20480);
  loadW(Ug, 2048, cw, 8, WL + 24576);
  loadW(Wg, 2048, cw, 8, WL + 32768);
  __syncthreads();                     // weights are block-local: no gsync

  for (int t = 0; t < T_; ++t) {
    // ---------- phase A: q/km/vm (192x12), g (192x8), kx/vx (64x8), xg (64x8)
    for (int idx = tid; idx < 2304; idx += NTHR) {
      int m = idx / 12, r = idx - m * 12, mat = r >> 2, j = r & 3;
      double acc = dotWL(mem32 + (size_t)m * 1024, WL + mat * 4096 + j * 1024, j << 3);
      int c = cq + j;
      if (mat == 0)      q32 [(size_t)m * 1024 + c] = (float)(acc + (double)bq[c]);
      else if (mat == 1) km32[(size_t)m * 1024 + c] = (float)(acc + (double)bk[c]);
      else               vm32[(size_t)m * 1024 + c] = (float)(acc + (double)bv[c]);
    }
    for (int idx = tid; idx < 1536; idx += NTHR) {
      int m = idx >> 3, j = idx & 7;
      double acc = dotWL(tmem32 + (size_t)m * 1024, WL + 24576 + j * 1024, (j & 3) << 3);
      g32[(size_t)m * 2048 + cw + j] = (float)acc;
    }
    for (int idx = tid; idx < 512; idx += NTHR) {
      int m = idx >> 3, r = idx & 7, mat = r >> 2, j = r & 3;
      const float* Ap = inputs + (size_t)m * (T_ * 1024) + (size_t)t * 1024;
      double acc = dotWL(Ap, WL + (mat ? 8192 : 4096) + j * 1024, j << 3);
      int c = cq + j;
      if (!mat) kx32[(size_t)m * 1024 + c] = (float)(acc + (double)bk[c]);
      else      vx32[(size_t)m * 1024 + c] = (float)(acc + (double)bv[c]);
    }
    for (int idx = tid; idx < 512; idx += NTHR) {
      int m = idx >> 3, j = idx & 7;
      const float* Ap = inputs + (size_t)m * (T_ * 1024) + (size_t)t * 1024;
      double acc = dotWL(Ap, WL + 32768 + j * 1024, (j & 3) << 3);
      int c = cw + j;
      xg32[(size_t)m * 2048 + c] = (float)(acc + (double)bg[c] + (double)bu[c]);
    }
    gsync(cnt, gen);

    // ---------- phase B: attention, 2 wave-jobs per block (512 total) ------
    {
      int wv = tid >> 6;
      if (wv < 2) {
        int bh = bid * 2 + wv;
        int b = bh >> 3, h = bh & 7, lane = tid & 63;
        int col = h * 128 + lane;
        double q0[3], q1[3], kk0[4], kk1[4], vv0[4], vv1[4];
#pragma unroll
        for (int s = 0; s < 3; ++s) {
          size_t r = (size_t)(b * 3 + s) * 1024 + col;
          q0[s] = (double)q32[r]; q1[s] = (double)q32[r + 64];
        }
#pragma unroll
        for (int j = 0; j < 3; ++j) {
          size_t r = (size_t)(b * 3 + j) * 1024 + col;
          kk0[j] = (double)km32[r]; kk1[j] = (double)km32[r + 64];
          vv0[j] = (double)vm32[r]; vv1[j] = (double)vm32[r + 64];
        }
        {
          size_t r = (size_t)b * 1024 + col;
          kk0[3] = (double)kx32[r]; kk1[3] = (double)kx32[r + 64];
          vv0[3] = (double)vx32[r]; vv1[3] = (double)vx32[r + 64];
        }
        const double scale = 0.08838834764831845;  // 1/sqrt(128)
        double p[3][4];
#pragma unroll
        for (int s = 0; s < 3; ++s)
#pragma unroll
          for (int j = 0; j < 4; ++j) {
            double d = q0[s] * kk0[j] + q1[s] * kk1[j];
#pragma unroll
            for (int off = 32; off > 0; off >>= 1) d += __shfl_xor(d, off);
            p[s][j] = d * scale;
          }
#pragma unroll
        for (int s = 0; s < 3; ++s) {
          double m = fmax(fmax(p[s][0], p[s][1]), fmax(p[s][2], p[s][3]));
          double e0 = exp(p[s][0] - m), e1 = exp(p[s][1] - m);
          double e2 = exp(p[s][2] - m), e3 = exp(p[s][3] - m);
          double inv = 1.0 / (e0 + e1 + e2 + e3);
          double o0 = (e0 * vv0[0] + e1 * vv0[1] + e2 * vv0[2] + e3 * vv0[3]) * inv;
          double o1 = (e0 * vv1[0] + e1 * vv1[1] + e2 * vv1[2] + e3 * vv1[3]) * inv;
          size_t r = (size_t)(b * 3 + s) * 1024 + col;
          o32[r] = (float)o0; o32[r + 64] = (float)o1;
        }
      }
    }
    gsync(cnt, gen);

    // ---------- phase C: nm = mem + o@Wo + bo (192 x own 4 cols) -----------
    for (int idx = tid; idx < 768; idx += NTHR) {
      int m = idx >> 2, j = idx & 3;
      double acc = dotWL(o32 + (size_t)m * 1024, WL + 12288 + j * 1024, j << 3);
      int c = cq + j; size_t id = (size_t)m * 1024 + c;
      double nv = mem64[id] + acc + (double)bo[c];
      nm64[id] = nv; nm32[id] = (float)nv;
    }
    gsync(cnt, gen);

    // ---------- phase D: h1 = relu(nm@W1 + b1) -----------------------------
    for (int idx = tid; idx < 768; idx += NTHR) {
      int m = idx >> 2, j = idx & 3;
      double acc = dotWL(nm32 + (size_t)m * 1024, WL + 16384 + j * 1024, j << 3);
      int c = cq + j;
      h132[(size_t)m * 1024 + c] = (float)fmax(acc + (double)b1[c], 0.0);
    }
    gsync(cnt, gen);

    // ---------- phase E: ml=relu(h1@W2+b2); gate; state update; emit -------
    for (int idx = tid; idx < 768; idx += NTHR) {
      int m = idx >> 2, j = idx & 3;
      double acc = dotWL(h132 + (size_t)m * 1024, WL + 20480 + j * 1024, j << 3);
      int c = cq + j; size_t id = (size_t)m * 1024 + c;
      double ml = fmax(acc + (double)b2[c], 0.0);
      double nm2 = nm64[id] + ml;
      int b = m / 3, s = m - b * 3;
      double ig = (double)xg32[(size_t)b * 2048 + c]        + (double)g32[(size_t)m * 2048 + c];
      double fg = (double)xg32[(size_t)b * 2048 + 1024 + c] + (double)g32[(size_t)m * 2048 + 1024 + c];
      double old = mem64[id];
      double nv = sigm_d(ig) * tanh(nm2) + sigm_d(fg) * old;
      out[(size_t)(b * T_ + t) * 3072 + s * 1024 + c] = (float)nv;
      mem64[id] = nv; mem32[id] = (float)nv; tmem32[id] = (float)tanh(nv);
    }
    gsync(cnt, gen);
  }
}

// ---------------------------------------------------------------------------
extern "C" void kernel_launch(void* const* d_in, const int* in_sizes, int n_in,
                              void* d_out, int out_size, void* d_ws, size_t ws_size,
                              hipStream_t stream) {
  (void)in_sizes; (void)n_in; (void)out_size;
  const float* inputs = (const float*)d_in[0];
  const float* memory = (const float*)d_in[1];
  const float* Wq = (const float*)d_in[2];  const float* bq = (const float*)d_in[3];
  const float* Wk = (const float*)d_in[4];  const float* bk = (const float*)d_in[5];
  const float* Wv = (const float*)d_in[6];  const float* bv = (const float*)d_in[7];
  const float* Wo = (const float*)d_in[8];  const float* bo = (const float*)d_in[9];
  const float* W1 = (const float*)d_in[10]; const float* b1 = (const float*)d_in[11];
  const float* W2 = (const float*)d_in[12]; const float* b2 = (const float*)d_in[13];
  const float* Wg = (const float*)d_in[14]; const float* bg = (const float*)d_in[15];
  const float* Ug = (const float*)d_in[16]; const float* bu = (const float*)d_in[17];
  float* out = (float*)d_out;

  // Footprint ~11.3 MB (ws = 64 MiB). Bail-signature if wrong: absmax 4.3125.
  if (ws_size < (size_t)16 * 1024 * 1024) return;

  char* ws = (char*)d_ws;
  size_t off = 0;
  auto alloc = [&](size_t bytes) -> void* {
    void* p = ws + off; off += (bytes + 255) & ~(size_t)255; return p;
  };
  unsigned* cnt = (unsigned*)alloc(256);
  unsigned* gen = (unsigned*)alloc(256);
  double* mem64 = (double*)alloc((size_t)196608 * 8);
  double* nm64  = (double*)alloc((size_t)196608 * 8);
  float* mem32  = (float*)alloc((size_t)196608 * 4);
  float* tmem32 = (float*)alloc((size_t)196608 * 4);
  float* nm32   = (float*)alloc((size_t)196608 * 4);
  float* o32    = (float*)alloc((size_t)196608 * 4);
  float* h132   = (float*)alloc((size_t)196608 * 4);
  float* q32    = (float*)alloc((size_t)196608 * 4);
  float* km32   = (float*)alloc((size_t)196608 * 4);
  float* vm32   = (float*)alloc((size_t)196608 * 4);
  float* g32    = (float*)alloc((size_t)192 * 2048 * 4);
  float* kx32   = (float*)alloc((size_t)64 * 1024 * 4);
  float* vx32   = (float*)alloc((size_t)64 * 1024 * 4);
  float* xg32   = (float*)alloc((size_t)64 * 2048 * 4);

  k_init<<<768, 256, 0, stream>>>(memory, mem64, mem32, tmem32, cnt, gen, 196608);
  k_fused<<<NBLK, NTHR, 0, stream>>>(inputs, Wq, Wk, Wv, Wo, W1, W2, Wg, Ug,
                                     bq, bk, bv, bo, b1, b2, bg, bu,
                                     mem64, nm64, mem32, tmem32, nm32, o32, h132,
                                     q32, km32, vm32, g32, kx32, vx32, xg32,
                                     cnt, gen, out);
}